// Round 1
// baseline (285.953 us; speedup 1.0000x reference)
//
#include <hip/hip_runtime.h>
#include <math.h>

// Problem constants (fixed by reference): B=32, D=64, H=W=64, K=512
#define KC      512
#define DD      64
#define NROWS   131072      // B*H*W
#define HWN     4096        // H*W
#define BSTRIDE 262144      // D*H*W
#define PITCH   68          // LDS row pitch (floats): +4 pad, keeps 16B alignment
#define TOTELEM 8388608.0f  // B*D*H*W

// ---- workspace layout (float offsets) ----
#define WS_ENORM  0         // [512]
#define WS_COUNTS 512       // [512]
#define WS_LOSS   1024      // [1]
#define WS_DW     1088      // [512*64]
#define WS_IDX    33856     // [131072] ints
#define WS_ZERO_BYTES 135424  // bytes covering [0, WS_DW+32768)

// ---- output layout (float offsets) ----
#define OUT_QUANT 0
#define OUT_LOSS  8388608
#define OUT_PERP  8388609
#define OUT_EMB   8388610
#define OUT_SM    8421378
#define OUT_EMAW  8421890

// K0: per-code squared norms
__global__ void k_enorm(const float* __restrict__ emb, float* __restrict__ enorm) {
    int k = blockIdx.x * blockDim.x + threadIdx.x;
    if (k >= KC) return;
    const float* r = emb + k * DD;
    float s0 = 0.f, s1 = 0.f, s2 = 0.f, s3 = 0.f;
#pragma unroll
    for (int d = 0; d < DD; d += 4) {
        s0 += r[d] * r[d];
        s1 += r[d + 1] * r[d + 1];
        s2 += r[d + 2] * r[d + 2];
        s3 += r[d + 3] * r[d + 3];
    }
    enorm[k] = (s0 + s1) + (s2 + s3);
}

// K1: argmin over codes for each row; counts histogram; idx store.
// 512 threads/block, 1 row/thread, grid = NROWS/512 = 256 blocks (1/CU).
// Embedding staged in LDS (pitch 68 floats); inner reads are wave-uniform -> broadcast.
__global__ __launch_bounds__(512, 2) void k_argmin(
        const float* __restrict__ x, const float* __restrict__ emb,
        const float* __restrict__ enorm_g, float* __restrict__ counts,
        int* __restrict__ idx_out) {
    __shared__ float se[KC * PITCH];   // 139264 B
    __shared__ float sen[KC];
    __shared__ float hist[KC];

    const int tid = threadIdx.x;

    // stage embedding: 8192 float4 chunks, 16 per thread, coalesced global reads
    for (int i = tid; i < (KC * DD) / 4; i += 512) {
        int base = i * 4;
        int k = base >> 6, d = base & 63;
        float4 v = reinterpret_cast<const float4*>(emb)[i];
        *reinterpret_cast<float4*>(&se[k * PITCH + d]) = v;
    }
    sen[tid] = enorm_g[tid];
    hist[tid] = 0.f;
    __syncthreads();

    const int n  = blockIdx.x * 512 + tid;
    const int b  = n >> 12;
    const int hw = n & 4095;
    const float* xp = x + b * BSTRIDE + hw;   // element (b, d, hw) at xp[d*4096]

    float row[DD];
    float f0 = 0.f, f1 = 0.f, f2 = 0.f, f3 = 0.f;
#pragma unroll
    for (int d = 0; d < DD; d += 4) {
        row[d]     = xp[d * HWN];
        row[d + 1] = xp[(d + 1) * HWN];
        row[d + 2] = xp[(d + 2) * HWN];
        row[d + 3] = xp[(d + 3) * HWN];
        f0 += row[d] * row[d];
        f1 += row[d + 1] * row[d + 1];
        f2 += row[d + 2] * row[d + 2];
        f3 += row[d + 3] * row[d + 3];
    }
    const float fn = (f0 + f1) + (f2 + f3);

    float best = 3.4e38f;
    int bi = 0;
    for (int k = 0; k < KC; k += 2) {
        const float* e0 = &se[k * PITCH];
        const float* e1 = e0 + PITCH;
        float a0 = 0.f, a1 = 0.f, a2 = 0.f, a3 = 0.f;
        float b0 = 0.f, b1 = 0.f, b2 = 0.f, b3 = 0.f;
#pragma unroll
        for (int d = 0; d < DD; d += 4) {
            a0 += row[d] * e0[d];
            a1 += row[d + 1] * e0[d + 1];
            a2 += row[d + 2] * e0[d + 2];
            a3 += row[d + 3] * e0[d + 3];
            b0 += row[d] * e1[d];
            b1 += row[d + 1] * e1[d + 1];
            b2 += row[d + 2] * e1[d + 2];
            b3 += row[d + 3] * e1[d + 3];
        }
        float dot0 = (a0 + a1) + (a2 + a3);
        float dot1 = (b0 + b1) + (b2 + b3);
        float dist0 = fn - 2.0f * dot0 + sen[k];
        float dist1 = fn - 2.0f * dot1 + sen[k + 1];
        if (dist0 < best) { best = dist0; bi = k; }       // strict <: first-min tie-break
        if (dist1 < best) { best = dist1; bi = k + 1; }
    }

    idx_out[n] = bi;
    atomicAdd(&hist[bi], 1.0f);
    __syncthreads();
    float h = hist[tid];
    if (h != 0.f) atomicAdd(&counts[tid], h);  // integer-valued floats: exact
}

// K2: quant_st write, loss partial, dw segment-sum.
// grid = B*D = 2048 blocks; block handles one (b,d) plane of 4096 elements.
__global__ void k_scatter(const float* __restrict__ x, const float* __restrict__ emb,
                          const int* __restrict__ idx, float* __restrict__ qout,
                          float* __restrict__ dw, float* __restrict__ loss_acc) {
    __shared__ float dwloc[KC];
    __shared__ float red[4];
    const int blk = blockIdx.x;
    const int b = blk >> 6, d = blk & 63;
    const int tid = threadIdx.x;   // 256

    for (int i = tid; i < KC; i += 256) dwloc[i] = 0.f;
    __syncthreads();

    const float* xp = x + b * BSTRIDE + d * HWN;
    float*       qp = qout + b * BSTRIDE + d * HWN;
    const int*   ip = idx + b * HWN;

    float ls = 0.f;
    for (int hw = tid; hw < HWN; hw += 256) {
        float xv = xp[hw];
        int   id = ip[hw];
        float ev = emb[id * DD + d];
        float t  = ev - xv;          // quant - x
        qp[hw]   = xv + t;           // x + (quant - x), matches reference rounding
        ls += t * t;
        atomicAdd(&dwloc[id], xv);
    }

    // block loss reduction: wave shuffle then 4-way LDS
#pragma unroll
    for (int o = 32; o > 0; o >>= 1) ls += __shfl_down(ls, o);
    if ((tid & 63) == 0) red[tid >> 6] = ls;
    __syncthreads();
    if (tid == 0) atomicAdd(loss_acc, (red[0] + red[1]) + (red[2] + red[3]));

    for (int i = tid; i < KC; i += 256) {
        float v = dwloc[i];
        if (v != 0.f) atomicAdd(&dw[i * DD + d], v);
    }
}

// K3: single block; scalars (loss, perplexity), smoothed cluster sizes.
__global__ void k_final(const float* __restrict__ counts, const float* __restrict__ ema_cs,
                        const float* __restrict__ loss_acc, float* __restrict__ out) {
    __shared__ float r1[8], r2[8];
    __shared__ float nb;
    const int t = threadIdx.x;   // 512

    float c   = counts[t];
    float ncs = 0.99f * ema_cs[t] + 0.01f * c;

    float s = ncs;
#pragma unroll
    for (int o = 32; o > 0; o >>= 1) s += __shfl_down(s, o);

    float p = c * (1.0f / 131072.0f);
    float e = (p > 0.f) ? p * logf(p) : 0.f;
#pragma unroll
    for (int o = 32; o > 0; o >>= 1) e += __shfl_down(e, o);

    if ((t & 63) == 0) { r1[t >> 6] = s; r2[t >> 6] = e; }
    __syncthreads();
    if (t == 0) {
        float n  = 0.f, es = 0.f;
#pragma unroll
        for (int i = 0; i < 8; ++i) { n += r1[i]; es += r2[i]; }
        nb = n;
        out[OUT_LOSS] = 0.25f * (loss_acc[0] / TOTELEM);
        out[OUT_PERP] = expf(-es);
    }
    __syncthreads();
    float n = nb;
    out[OUT_SM + t] = (ncs + 1e-5f) / (n + 0.00512f) * n;   // (ncs+EPS)/(n+K*EPS)*n
}

// K4: new_ema_w and new_embedding (32768 elements).
__global__ void k_emb(const float* __restrict__ ema_w, const float* __restrict__ dw,
                      const float* __restrict__ sm, float* __restrict__ out_emaw,
                      float* __restrict__ out_emb) {
    int i = blockIdx.x * 256 + threadIdx.x;
    float nw = 0.99f * ema_w[i] + 0.01f * dw[i];
    out_emaw[i] = nw;
    out_emb[i]  = nw / sm[i >> 6];
}

extern "C" void kernel_launch(void* const* d_in, const int* in_sizes, int n_in,
                              void* d_out, int out_size, void* d_ws, size_t ws_size,
                              hipStream_t stream) {
    const float* x      = (const float*)d_in[0];
    const float* emb    = (const float*)d_in[1];
    const float* ema_cs = (const float*)d_in[2];
    const float* ema_w  = (const float*)d_in[3];
    float* out = (float*)d_out;

    float* wsf     = (float*)d_ws;
    float* enorm   = wsf + WS_ENORM;
    float* counts  = wsf + WS_COUNTS;
    float* loss    = wsf + WS_LOSS;
    float* dw      = wsf + WS_DW;
    int*   idx     = (int*)(wsf + WS_IDX);

    hipMemsetAsync(d_ws, 0, WS_ZERO_BYTES, stream);

    k_enorm  <<<2,    256, 0, stream>>>(emb, enorm);
    k_argmin <<<256,  512, 0, stream>>>(x, emb, enorm, counts, idx);
    k_scatter<<<2048, 256, 0, stream>>>(x, emb, idx, out + OUT_QUANT, dw, loss);
    k_final  <<<1,    512, 0, stream>>>(counts, ema_cs, loss, out);
    k_emb    <<<128,  256, 0, stream>>>(ema_w, dw, out + OUT_SM, out + OUT_EMAW,
                                        out + OUT_EMB);
}